// Round 12
// baseline (258.283 us; speedup 1.0000x reference)
//
#include <hip/hip_runtime.h>
#include <hip/hip_bf16.h>

#define NPTS (4096 * 32)

typedef __bf16 bf16x8 __attribute__((ext_vector_type(8)));
typedef float f32x4 __attribute__((ext_vector_type(4)));

__device__ __forceinline__ float bf2f(unsigned short u) {
    union { unsigned u32; float f; } v;
    v.u32 = ((unsigned)u) << 16;
    return v.f;
}
__device__ __forceinline__ unsigned short f2bf(float f) {
    __hip_bfloat16 h = __float2bfloat16(f);
    union { __hip_bfloat16 h; unsigned short u; } v;
    v.h = h;
    return v.u;
}

static __device__ const float    LVL_SCALE[10] = {15.f,31.f,63.f,127.f,255.f,511.f,1023.f,2047.f,4095.f,8191.f};
static __device__ const unsigned LVL_RES[10]   = {16u,32u,64u,128u,256u,512u,1024u,2048u,4096u,8192u};
static __device__ const unsigned LVL_OFF[10]   = {0u,4096u,36864u,299008u,2396160u,4493312u,6590464u,8687616u,10784768u,12881920u};
static __device__ const unsigned LVL_MASK[10]  = {4095u,32767u,262143u,2097151u,2097151u,2097151u,2097151u,2097151u,2097151u};

// ---------------- front1: encode (blocks [0,512)) + weight prep (blocks [512,1024))
// No big LDS, VGPR ~32 -> encode keeps full occupancy; dirw moved to its own kernel.
__global__ __launch_bounds__(256) void k_front1(const float* __restrict__ coords,
                                                const float* __restrict__ table,
                                                unsigned short* __restrict__ featsb,
                                                const float* __restrict__ W0,
                                                const float* __restrict__ W1,
                                                const float* __restrict__ Wd0,
                                                const float* __restrict__ Wd1,
                                                unsigned short* __restrict__ W0t,
                                                unsigned short* __restrict__ W1t,
                                                unsigned short* __restrict__ Wd0t,
                                                unsigned short* __restrict__ Wd1t) {
    int bid = blockIdx.x;
    int t = threadIdx.x;
    if (bid < 512) {
        // ---- encode: contract + 10-level grid gather -> featsb [N][64] bf16 (zero k>=40)
        int n = bid * 256 + t;
        float x = coords[(size_t)n*3+0], y = coords[(size_t)n*3+1], z = coords[(size_t)n*3+2];
        float sq = x*x + y*y + z*z;
        float nn = sqrtf(fmaxf(sq, 1e-12f));
        if (nn > 1.0f) {
            float inv = 1.0f / nn;
            float s = 2.0f - inv;
            x = s * (x * inv); y = s * (y * inv); z = s * (z * inv);
        }
        float px = (x * 0.5f + 1.0f) * 0.5f;
        float py = (y * 0.5f + 1.0f) * 0.5f;
        float pz = (z * 0.5f + 1.0f) * 0.5f;
        const float4* tab = (const float4*)table;
        unsigned short* fr = featsb + (size_t)n * 64;
#pragma unroll
        for (int l = 0; l < 10; ++l) {
            float sc = LVL_SCALE[l];
            unsigned res = LVL_RES[l], mask = LVL_MASK[l];
            const float4* tl = tab + LVL_OFF[l];
            float fx = px*sc + 0.5f, fy = py*sc + 0.5f, fz = pz*sc + 0.5f;
            float x0 = floorf(fx), y0 = floorf(fy), z0 = floorf(fz);
            float tx = fx - x0, ty = fy - y0, tz = fz - z0;
            unsigned cx = (unsigned)x0, cy = (unsigned)y0, cz = (unsigned)z0;
            float ax = 0.f, ay = 0.f, az = 0.f, aw = 0.f;
#pragma unroll
            for (int dx = 0; dx < 2; ++dx)
#pragma unroll
            for (int dy = 0; dy < 2; ++dy)
#pragma unroll
            for (int dz = 0; dz < 2; ++dz) {
                unsigned ux = cx + dx, uy = cy + dy, uz = cz + dz;
                unsigned idx;
                if (l < 4) idx = ((ux * res + uy) * res + uz) & mask;
                else       idx = (ux ^ (uy * 2654435761u) ^ (uz * 805459861u)) & mask;
                float w = (dx ? tx : 1.0f - tx) * (dy ? ty : 1.0f - ty) * (dz ? tz : 1.0f - tz);
                float4 v = tl[idx];
                ax += w * v.x; ay += w * v.y; az += w * v.z; aw += w * v.w;
            }
            ushort4 s;
            s.x = f2bf(ax); s.y = f2bf(ay); s.z = f2bf(az); s.w = f2bf(aw);
            *(ushort4*)(fr + l * 4) = s;
        }
        ushort4 z4; z4.x = z4.y = z4.z = z4.w = 0;
#pragma unroll
        for (int k = 40; k < 64; k += 4) *(ushort4*)(fr + k) = z4;
    } else {
        // ---- weight prep
        int i = (bid - 512) * 256 + t;  // i < 131072
        if (i < 65536) {
            int c = i >> 8, k = i & 255;
            W0t[i] = f2bf(W0[(size_t)k * 256 + c]);
        }
        {
            int c = i >> 9, k = i & 511;
            W1t[i] = f2bf(W1[(size_t)k * 256 + c]);
        }
        if (i < 4608) {  // 64*72
            int c = i / 72, k = i % 72;
            Wd0t[i] = (k < 40) ? f2bf(Wd0[(size_t)k * 64 + c]) : 0;
        }
        if (i < 18432) {  // 256*72
            int c = i / 72, k = i % 72;
            Wd1t[i] = (k < 64) ? f2bf(Wd1[(size_t)k * 256 + c]) : 0;
        }
    }
}

// ---------------- dirw v2: 256 blocks x 16 batch rows; W rows staged ONCE in LDS (16x less traffic)
__global__ __launch_bounds__(256) void k_dirw(const float* __restrict__ vd,
                                              const float* __restrict__ W0,
                                              const float* __restrict__ b0,
                                              const float* __restrict__ W1,
                                              const float* __restrict__ b1,
                                              float* __restrict__ deW0,
                                              float* __restrict__ deW1) {
    __shared__ float sW0r[27 * 256];
    __shared__ float sW1r[27 * 256];
    __shared__ float de[27];
    int t = threadIdx.x;
    int bbase = blockIdx.x * 16;
    for (int i = t; i < 27 * 256; i += 256) {
        int k = i >> 8, c = i & 255;
        sW0r[i] = W0[(size_t)(256 + k) * 256 + c];
        sW1r[i] = W1[(size_t)(512 + k) * 256 + c];
    }
    __syncthreads();
    float vb0 = b0[t], vb1 = b1[t];
    for (int j = 0; j < 16; ++j) {
        int b = bbase + j;
        if (t < 27) {
            float v;
            const float HPI = 0.5f * 3.14159265358979323846f;
            if (t < 3) {
                v = vd[(size_t)b*3 + t];
            } else if (t < 15) {
                int i = (t - 3) / 3, jj = (t - 3) % 3;
                v = sinf(vd[(size_t)b*3 + jj] * (float)(1 << i));
            } else {
                int i = (t - 15) / 3, jj = (t - 15) % 3;
                v = sinf(vd[(size_t)b*3 + jj] * (float)(1 << i) + HPI);
            }
            de[t] = v;
        }
        __syncthreads();
        float a0 = vb0, a1 = vb1;
#pragma unroll
        for (int k = 0; k < 27; ++k) {
            float d = de[k];
            a0 += d * sW0r[k * 256 + t];
            a1 += d * sW1r[k * 256 + t];
        }
        deW0[(size_t)b*256 + t] = a0;
        deW1[(size_t)b*256 + t] = a1;
        __syncthreads();  // protect de before next overwrite
    }
}

// ---------------- density MLP (MFMA): featsb[64rows][64k] -> h[64][64] -> x[64][256] bf16 + density
__global__ __launch_bounds__(512, 4) void k_mlp0(const unsigned short* __restrict__ featsb,
                                                 const unsigned short* __restrict__ Wd0t,
                                                 const unsigned short* __restrict__ Wd1t,
                                                 const float* __restrict__ bd0,
                                                 const float* __restrict__ bd1,
                                                 unsigned short* __restrict__ xb,
                                                 float* __restrict__ out) {
    __shared__ __align__(16) unsigned short sWd1[256 * 72];
    __shared__ __align__(16) unsigned short sWd0[64 * 72];
    __shared__ __align__(16) unsigned short sF[64 * 72];
    __shared__ __align__(16) unsigned short sH[64 * 72];
    int t = threadIdx.x;
    int r0 = blockIdx.x * 64;
    {
        int r = t >> 3, kq = (t & 7) * 8;
        *(int4*)(sF + r * 72 + kq)   = *(const int4*)(featsb + (size_t)(r0 + r) * 64 + kq);
        *(int4*)(sWd0 + r * 72 + kq) = *(const int4*)(Wd0t + r * 72 + kq);
#pragma unroll
        for (int j = 0; j < 4; ++j) {
            int idx = t + j * 512;
            int c = idx >> 3, k = (idx & 7) * 8;
            *(int4*)(sWd1 + c * 72 + k) = *(const int4*)(Wd1t + c * 72 + k);
        }
    }
    __syncthreads();
    int lane = t & 63, wid = t >> 6, cl = lane & 15, q = lane >> 4;
    {
        int wr = wid >> 1, wc = wid & 1;
        f32x4 acc[2] = {};
#pragma unroll
        for (int ks = 0; ks < 2; ++ks) {
            bf16x8 af = *(const bf16x8*)(sF + (wr * 16 + cl) * 72 + ks * 32 + q * 8);
#pragma unroll
            for (int n = 0; n < 2; ++n) {
                bf16x8 bf = *(const bf16x8*)(sWd0 + (wc * 32 + n * 16 + cl) * 72 + ks * 32 + q * 8);
                acc[n] = __builtin_amdgcn_mfma_f32_16x16x32_bf16(af, bf, acc[n], 0, 0, 0);
            }
        }
#pragma unroll
        for (int n = 0; n < 2; ++n) {
            int c = wc * 32 + n * 16 + cl;
            float bv = bd0[c];
#pragma unroll
            for (int i = 0; i < 4; ++i) {
                int r = wr * 16 + q * 4 + i;
                sH[r * 72 + c] = f2bf(fmaxf(acc[n][i] + bv, 0.f));
            }
        }
    }
    __syncthreads();
    {
        int wr = wid >> 2, wc = wid & 3;
        f32x4 acc[2][4] = {};
#pragma unroll
        for (int ks = 0; ks < 2; ++ks) {
            bf16x8 af[2], bf[4];
#pragma unroll
            for (int m = 0; m < 2; ++m)
                af[m] = *(const bf16x8*)(sH + (wr * 32 + m * 16 + cl) * 72 + ks * 32 + q * 8);
#pragma unroll
            for (int n = 0; n < 4; ++n)
                bf[n] = *(const bf16x8*)(sWd1 + (wc * 64 + n * 16 + cl) * 72 + ks * 32 + q * 8);
#pragma unroll
            for (int m = 0; m < 2; ++m)
#pragma unroll
                for (int n = 0; n < 4; ++n)
                    acc[m][n] = __builtin_amdgcn_mfma_f32_16x16x32_bf16(af[m], bf[n], acc[m][n], 0, 0, 0);
        }
#pragma unroll
        for (int n = 0; n < 4; ++n) {
            int c = wc * 64 + n * 16 + cl;
            float bv = bd1[c];
#pragma unroll
            for (int m = 0; m < 2; ++m) {
#pragma unroll
                for (int i = 0; i < 4; ++i) {
                    int r = wr * 32 + m * 16 + q * 4 + i;
                    float v = acc[m][n][i] + bv;
                    xb[(size_t)(r0 + r) * 256 + c] = f2bf(v);
                    if (n == 0 && wc == 0 && cl == 0) {
                        float d = v - 1.0f;
                        float sp = fmaxf(d, 0.0f) + log1pf(expf(-fabsf(d)));
                        out[(size_t)(r0 + r) * 4] = sp;
                    }
                }
            }
        }
    }
}

// ---------------- fused G3+G4 (round-9 proven, FROZEN):
// phase1: h0 = relu(x@W0 + deW0) -> sH0 ; acc2 = x@W1[256:512]  (af reused, two B passes)
// phase2: acc2 += h0@W1[0:256] ; h1 = relu(acc2 + deW1) -> LDS ; rgb = sigmoid(h1@Wr+br)
__global__ __launch_bounds__(512, 2) void k_g34(const unsigned short* __restrict__ xb,
                                                const unsigned short* __restrict__ W0t,  // [256][256]
                                                const unsigned short* __restrict__ W1t,  // [256][512]
                                                const float* __restrict__ deW0,
                                                const float* __restrict__ deW1,
                                                const float* __restrict__ Wr,
                                                const float* __restrict__ br,
                                                float* __restrict__ out) {
    __shared__ __align__(16) unsigned short sH0[4][64 * 72];  // 36864 B (h1 [64][264] reuses this)
    __shared__ __align__(16) unsigned short sB[256 * 40];     // 20480 B, K=32 chunk
    __shared__ float sWr[768];                                // 3072 B
    int t = threadIdx.x;
    int lane = t & 63, wid = t >> 6;
    int wr = wid >> 2, wc = wid & 3;   // wave tile 32 x 64
    int cl = lane & 15, q = lane >> 4;
    int r0 = blockIdx.x * 64;
    for (int i = t; i < 768; i += 512) sWr[i] = Wr[i];

    int bc = t >> 1, bh = (t & 1) * 16;  // B stage: col, k-sub
    const unsigned short* W0p = W0t + (size_t)bc * 256 + bh;
    const unsigned short* W1p = W1t + (size_t)bc * 512 + bh;
    const unsigned short* Arow0 = xb + (size_t)(r0 + wr * 32 + cl) * 256 + q * 8;
    const unsigned short* Arow1 = Arow0 + 16 * 256;

    f32x4 acc1[2][4] = {};
    f32x4 acc2[2][4] = {};

    // ---- phase 1: K=256 in 8 chunks of 32
    for (int c8 = 0; c8 < 8; ++c8) {
        int k0 = c8 * 32;
        bf16x8 af[2];
        af[0] = *(const bf16x8*)(Arow0 + k0);
        af[1] = *(const bf16x8*)(Arow1 + k0);
        int4 b0 = *(const int4*)(W0p + k0);
        int4 b1 = *(const int4*)(W0p + k0 + 8);
        __syncthreads();
        *(int4*)(sB + bc * 40 + bh)     = b0;
        *(int4*)(sB + bc * 40 + bh + 8) = b1;
        __syncthreads();
        {
            bf16x8 bf[4];
#pragma unroll
            for (int n = 0; n < 4; ++n)
                bf[n] = *(const bf16x8*)(sB + (wc * 64 + n * 16 + cl) * 40 + q * 8);
#pragma unroll
            for (int m = 0; m < 2; ++m)
#pragma unroll
                for (int n = 0; n < 4; ++n)
                    acc1[m][n] = __builtin_amdgcn_mfma_f32_16x16x32_bf16(af[m], bf[n], acc1[m][n], 0, 0, 0);
        }
        int4 c0 = *(const int4*)(W1p + 256 + k0);
        int4 c1 = *(const int4*)(W1p + 256 + k0 + 8);
        __syncthreads();
        *(int4*)(sB + bc * 40 + bh)     = c0;
        *(int4*)(sB + bc * 40 + bh + 8) = c1;
        __syncthreads();
        {
            bf16x8 bf[4];
#pragma unroll
            for (int n = 0; n < 4; ++n)
                bf[n] = *(const bf16x8*)(sB + (wc * 64 + n * 16 + cl) * 40 + q * 8);
#pragma unroll
            for (int m = 0; m < 2; ++m)
#pragma unroll
                for (int n = 0; n < 4; ++n)
                    acc2[m][n] = __builtin_amdgcn_mfma_f32_16x16x32_bf16(af[m], bf[n], acc2[m][n], 0, 0, 0);
        }
    }
    // ---- h0 epilogue -> sH0 K-tiles (each wave writes tile wc only)
#pragma unroll
    for (int m = 0; m < 2; ++m) {
        int rb = wr * 32 + m * 16;
        const float* dwp = deW0 + (size_t)((r0 + rb) >> 5) * 256;
#pragma unroll
        for (int n = 0; n < 4; ++n) {
            int c = wc * 64 + n * 16 + cl;
            float dv = dwp[c];
#pragma unroll
            for (int i = 0; i < 4; ++i) {
                int r = rb + q * 4 + i;
                sH0[wc][r * 72 + (c & 63)] = f2bf(fmaxf(acc1[m][n][i] + dv, 0.f));
            }
        }
    }
    __syncthreads();
    // ---- phase 2: acc2 += h0 @ W1lo, 8 chunks of 32
    for (int c8 = 0; c8 < 8; ++c8) {
        int k0 = c8 * 32;
        bf16x8 af[2];
#pragma unroll
        for (int m = 0; m < 2; ++m)
            af[m] = *(const bf16x8*)(&sH0[k0 >> 6][(wr * 32 + m * 16 + cl) * 72 + (k0 & 63) + q * 8]);
        int4 b0 = *(const int4*)(W1p + k0);
        int4 b1 = *(const int4*)(W1p + k0 + 8);
        __syncthreads();
        *(int4*)(sB + bc * 40 + bh)     = b0;
        *(int4*)(sB + bc * 40 + bh + 8) = b1;
        __syncthreads();
        bf16x8 bf[4];
#pragma unroll
        for (int n = 0; n < 4; ++n)
            bf[n] = *(const bf16x8*)(sB + (wc * 64 + n * 16 + cl) * 40 + q * 8);
#pragma unroll
        for (int m = 0; m < 2; ++m)
#pragma unroll
            for (int n = 0; n < 4; ++n)
                acc2[m][n] = __builtin_amdgcn_mfma_f32_16x16x32_bf16(af[m], bf[n], acc2[m][n], 0, 0, 0);
    }
    __syncthreads();  // all sH0 reads done before reuse as h1
    // ---- h1 epilogue -> [64][264] over sH0, then fused Wr reduce
    unsigned short* sH1 = &sH0[0][0];
#pragma unroll
    for (int m = 0; m < 2; ++m) {
        int rb = wr * 32 + m * 16;
        const float* dwp = deW1 + (size_t)((r0 + rb) >> 5) * 256;
#pragma unroll
        for (int n = 0; n < 4; ++n) {
            int c = wc * 64 + n * 16 + cl;
            float dv = dwp[c];
#pragma unroll
            for (int i = 0; i < 4; ++i) {
                int r = rb + q * 4 + i;
                sH1[r * 264 + c] = f2bf(fmaxf(acc2[m][n][i] + dv, 0.f));
            }
        }
    }
    __syncthreads();
    if (t < 384) {  // 64 rows x 3 ch x 2 halves
        int r = t / 6, rem = t % 6, j = rem >> 1, half = rem & 1;
        float a = 0.f;
        const unsigned short* hp = sH1 + r * 264 + half * 128;
        const float* wp = sWr + (half * 128) * 3 + j;
        for (int c = 0; c < 128; ++c) a += bf2f(hp[c]) * wp[c * 3];
        a += __shfl_xor(a, 1);
        if (!half) {
            a += br[j];
            float s = 1.0f / (1.0f + expf(-a));
            out[(size_t)(r0 + r) * 4 + 1 + j] = s * 1.002f - 0.001f;
        }
    }
}

extern "C" void kernel_launch(void* const* d_in, const int* in_sizes, int n_in,
                              void* d_out, int out_size, void* d_ws, size_t ws_size,
                              hipStream_t stream) {
    const float* coords   = (const float*)d_in[0];
    const float* viewdirs = (const float*)d_in[1];
    const float* table    = (const float*)d_in[2];
    const float* Wd0      = (const float*)d_in[3];
    const float* bd0      = (const float*)d_in[4];
    const float* Wd1      = (const float*)d_in[5];
    const float* bd1      = (const float*)d_in[6];
    const float* W0       = (const float*)d_in[7];
    const float* b0       = (const float*)d_in[8];
    const float* W1       = (const float*)d_in[9];
    const float* b1       = (const float*)d_in[10];
    const float* Wr       = (const float*)d_in[11];
    const float* br       = (const float*)d_in[12];
    float* out = (float*)d_out;

    const size_t N = NPTS;
    unsigned short* ws = (unsigned short*)d_ws;
    unsigned short* featsb = ws;                       // N*64 bf16 (padded K)
    unsigned short* xb     = featsb + N * 64;          // N*256 bf16
    float* deW0 = (float*)(xb + N * 256);              // 4096*256 f32
    float* deW1 = deW0 + 4096 * 256;                   // 4096*256 f32
    unsigned short* W0t  = (unsigned short*)(deW1 + 4096 * 256); // 256*256
    unsigned short* W1t  = W0t + 65536;                // 256*512
    unsigned short* Wd0t = W1t + 131072;               // 64*72
    unsigned short* Wd1t = Wd0t + 4608;                // 256*72

    k_front1<<<1024, 256, 0, stream>>>(coords, table, featsb,
                                       W0, W1, Wd0, Wd1, W0t, W1t, Wd0t, Wd1t);
    k_dirw<<<256, 256, 0, stream>>>(viewdirs, W0, b0, W1, b1, deW0, deW1);
    k_mlp0<<<NPTS / 64, 512, 0, stream>>>(featsb, Wd0t, Wd1t, bd0, bd1, xb, out);
    k_g34<<<NPTS / 64, 512, 0, stream>>>(xb, W0t, W1t, deW0, deW1, Wr, br, out);
}

// Round 13
// 249.935 us; speedup vs baseline: 1.0334x; 1.0334x over previous
//
#include <hip/hip_runtime.h>
#include <hip/hip_bf16.h>

#define NPTS (4096 * 32)

typedef __bf16 bf16x8 __attribute__((ext_vector_type(8)));
typedef float f32x4 __attribute__((ext_vector_type(4)));

__device__ __forceinline__ float bf2f(unsigned short u) {
    union { unsigned u32; float f; } v;
    v.u32 = ((unsigned)u) << 16;
    return v.f;
}
__device__ __forceinline__ unsigned short f2bf(float f) {
    __hip_bfloat16 h = __float2bfloat16(f);
    union { __hip_bfloat16 h; unsigned short u; } v;
    v.h = h;
    return v.u;
}

static __device__ const float    LVL_SCALE[10] = {15.f,31.f,63.f,127.f,255.f,511.f,1023.f,2047.f,4095.f,8191.f};
static __device__ const unsigned LVL_RES[10]   = {16u,32u,64u,128u,256u,512u,1024u,2048u,4096u,8192u};
static __device__ const unsigned LVL_OFF[10]   = {0u,4096u,36864u,299008u,2396160u,4493312u,6590464u,8687616u,10784768u,12881920u};
static __device__ const unsigned LVL_MASK[10]  = {4095u,32767u,262143u,2097151u,2097151u,2097151u,2097151u,2097151u,2097151u};

// ---------------- fused front v3: one launch, branch by block range
// blocks [0,512): encode (long pole, first)
// blocks [512,1024): weight prep
// blocks [1024,1280): dirw, 16 batch rows/block, REGISTER-staged W rows (traffic 226->14 MB)
__global__ __launch_bounds__(256) void k_front(const float* __restrict__ coords,
                                               const float* __restrict__ table,
                                               unsigned short* __restrict__ featsb,
                                               const float* __restrict__ W0,
                                               const float* __restrict__ W1,
                                               const float* __restrict__ Wd0,
                                               const float* __restrict__ Wd1,
                                               unsigned short* __restrict__ W0t,
                                               unsigned short* __restrict__ W1t,
                                               unsigned short* __restrict__ Wd0t,
                                               unsigned short* __restrict__ Wd1t,
                                               const float* __restrict__ vd,
                                               const float* __restrict__ b0,
                                               const float* __restrict__ b1,
                                               float* __restrict__ deW0,
                                               float* __restrict__ deW1) {
    __shared__ float de[27];
    int bid = blockIdx.x;
    int t = threadIdx.x;
    if (bid < 512) {
        // ---- encode: contract + 10-level grid gather -> featsb [N][64] bf16 (zero k>=40)
        int n = bid * 256 + t;
        float x = coords[(size_t)n*3+0], y = coords[(size_t)n*3+1], z = coords[(size_t)n*3+2];
        float sq = x*x + y*y + z*z;
        float nn = sqrtf(fmaxf(sq, 1e-12f));
        if (nn > 1.0f) {
            float inv = 1.0f / nn;
            float s = 2.0f - inv;
            x = s * (x * inv); y = s * (y * inv); z = s * (z * inv);
        }
        float px = (x * 0.5f + 1.0f) * 0.5f;
        float py = (y * 0.5f + 1.0f) * 0.5f;
        float pz = (z * 0.5f + 1.0f) * 0.5f;
        const float4* tab = (const float4*)table;
        unsigned short* fr = featsb + (size_t)n * 64;
#pragma unroll
        for (int l = 0; l < 10; ++l) {
            float sc = LVL_SCALE[l];
            unsigned res = LVL_RES[l], mask = LVL_MASK[l];
            const float4* tl = tab + LVL_OFF[l];
            float fx = px*sc + 0.5f, fy = py*sc + 0.5f, fz = pz*sc + 0.5f;
            float x0 = floorf(fx), y0 = floorf(fy), z0 = floorf(fz);
            float tx = fx - x0, ty = fy - y0, tz = fz - z0;
            unsigned cx = (unsigned)x0, cy = (unsigned)y0, cz = (unsigned)z0;
            float ax = 0.f, ay = 0.f, az = 0.f, aw = 0.f;
#pragma unroll
            for (int dx = 0; dx < 2; ++dx)
#pragma unroll
            for (int dy = 0; dy < 2; ++dy)
#pragma unroll
            for (int dz = 0; dz < 2; ++dz) {
                unsigned ux = cx + dx, uy = cy + dy, uz = cz + dz;
                unsigned idx;
                if (l < 4) idx = ((ux * res + uy) * res + uz) & mask;
                else       idx = (ux ^ (uy * 2654435761u) ^ (uz * 805459861u)) & mask;
                float w = (dx ? tx : 1.0f - tx) * (dy ? ty : 1.0f - ty) * (dz ? tz : 1.0f - tz);
                float4 v = tl[idx];
                ax += w * v.x; ay += w * v.y; az += w * v.z; aw += w * v.w;
            }
            ushort4 s;
            s.x = f2bf(ax); s.y = f2bf(ay); s.z = f2bf(az); s.w = f2bf(aw);
            *(ushort4*)(fr + l * 4) = s;
        }
        ushort4 z4; z4.x = z4.y = z4.z = z4.w = 0;
#pragma unroll
        for (int k = 40; k < 64; k += 4) *(ushort4*)(fr + k) = z4;
    } else if (bid < 1024) {
        // ---- weight prep
        int i = (bid - 512) * 256 + t;  // i < 131072
        if (i < 65536) {
            int c = i >> 8, k = i & 255;
            W0t[i] = f2bf(W0[(size_t)k * 256 + c]);
        }
        {
            int c = i >> 9, k = i & 511;
            W1t[i] = f2bf(W1[(size_t)k * 256 + c]);
        }
        if (i < 4608) {  // 64*72
            int c = i / 72, k = i % 72;
            Wd0t[i] = (k < 40) ? f2bf(Wd0[(size_t)k * 64 + c]) : 0;
        }
        if (i < 18432) {  // 256*72
            int c = i / 72, k = i % 72;
            Wd1t[i] = (k < 64) ? f2bf(Wd1[(size_t)k * 256 + c]) : 0;
        }
    } else {
        // ---- dirw: 16 rows/block, W rows register-staged once
        float w0r[27], w1r[27];
#pragma unroll
        for (int k = 0; k < 27; ++k) {
            w0r[k] = W0[(size_t)(256 + k) * 256 + t];
            w1r[k] = W1[(size_t)(512 + k) * 256 + t];
        }
        float vb0 = b0[t], vb1 = b1[t];
        int bbase = (bid - 1024) * 16;
        for (int j = 0; j < 16; ++j) {
            int b = bbase + j;
            if (t < 27) {
                float v;
                const float HPI = 0.5f * 3.14159265358979323846f;
                if (t < 3) {
                    v = vd[(size_t)b*3 + t];
                } else if (t < 15) {
                    int i = (t - 3) / 3, jj = (t - 3) % 3;
                    v = sinf(vd[(size_t)b*3 + jj] * (float)(1 << i));
                } else {
                    int i = (t - 15) / 3, jj = (t - 15) % 3;
                    v = sinf(vd[(size_t)b*3 + jj] * (float)(1 << i) + HPI);
                }
                de[t] = v;
            }
            __syncthreads();
            float a0 = vb0, a1 = vb1;
#pragma unroll
            for (int k = 0; k < 27; ++k) {
                float d = de[k];
                a0 += d * w0r[k];
                a1 += d * w1r[k];
            }
            deW0[(size_t)b*256 + t] = a0;
            deW1[(size_t)b*256 + t] = a1;
            __syncthreads();  // protect de before next row's overwrite
        }
    }
}

// ---------------- density MLP (MFMA): featsb[64rows][64k] -> h[64][64] -> x[64][256] bf16 + density
__global__ __launch_bounds__(512, 4) void k_mlp0(const unsigned short* __restrict__ featsb,
                                                 const unsigned short* __restrict__ Wd0t,
                                                 const unsigned short* __restrict__ Wd1t,
                                                 const float* __restrict__ bd0,
                                                 const float* __restrict__ bd1,
                                                 unsigned short* __restrict__ xb,
                                                 float* __restrict__ out) {
    __shared__ __align__(16) unsigned short sWd1[256 * 72];
    __shared__ __align__(16) unsigned short sWd0[64 * 72];
    __shared__ __align__(16) unsigned short sF[64 * 72];
    __shared__ __align__(16) unsigned short sH[64 * 72];
    int t = threadIdx.x;
    int r0 = blockIdx.x * 64;
    {
        int r = t >> 3, kq = (t & 7) * 8;
        *(int4*)(sF + r * 72 + kq)   = *(const int4*)(featsb + (size_t)(r0 + r) * 64 + kq);
        *(int4*)(sWd0 + r * 72 + kq) = *(const int4*)(Wd0t + r * 72 + kq);
#pragma unroll
        for (int j = 0; j < 4; ++j) {
            int idx = t + j * 512;
            int c = idx >> 3, k = (idx & 7) * 8;
            *(int4*)(sWd1 + c * 72 + k) = *(const int4*)(Wd1t + c * 72 + k);
        }
    }
    __syncthreads();
    int lane = t & 63, wid = t >> 6, cl = lane & 15, q = lane >> 4;
    {
        int wr = wid >> 1, wc = wid & 1;
        f32x4 acc[2] = {};
#pragma unroll
        for (int ks = 0; ks < 2; ++ks) {
            bf16x8 af = *(const bf16x8*)(sF + (wr * 16 + cl) * 72 + ks * 32 + q * 8);
#pragma unroll
            for (int n = 0; n < 2; ++n) {
                bf16x8 bf = *(const bf16x8*)(sWd0 + (wc * 32 + n * 16 + cl) * 72 + ks * 32 + q * 8);
                acc[n] = __builtin_amdgcn_mfma_f32_16x16x32_bf16(af, bf, acc[n], 0, 0, 0);
            }
        }
#pragma unroll
        for (int n = 0; n < 2; ++n) {
            int c = wc * 32 + n * 16 + cl;
            float bv = bd0[c];
#pragma unroll
            for (int i = 0; i < 4; ++i) {
                int r = wr * 16 + q * 4 + i;
                sH[r * 72 + c] = f2bf(fmaxf(acc[n][i] + bv, 0.f));
            }
        }
    }
    __syncthreads();
    {
        int wr = wid >> 2, wc = wid & 3;
        f32x4 acc[2][4] = {};
#pragma unroll
        for (int ks = 0; ks < 2; ++ks) {
            bf16x8 af[2], bf[4];
#pragma unroll
            for (int m = 0; m < 2; ++m)
                af[m] = *(const bf16x8*)(sH + (wr * 32 + m * 16 + cl) * 72 + ks * 32 + q * 8);
#pragma unroll
            for (int n = 0; n < 4; ++n)
                bf[n] = *(const bf16x8*)(sWd1 + (wc * 64 + n * 16 + cl) * 72 + ks * 32 + q * 8);
#pragma unroll
            for (int m = 0; m < 2; ++m)
#pragma unroll
                for (int n = 0; n < 4; ++n)
                    acc[m][n] = __builtin_amdgcn_mfma_f32_16x16x32_bf16(af[m], bf[n], acc[m][n], 0, 0, 0);
        }
#pragma unroll
        for (int n = 0; n < 4; ++n) {
            int c = wc * 64 + n * 16 + cl;
            float bv = bd1[c];
#pragma unroll
            for (int m = 0; m < 2; ++m) {
#pragma unroll
                for (int i = 0; i < 4; ++i) {
                    int r = wr * 32 + m * 16 + q * 4 + i;
                    float v = acc[m][n][i] + bv;
                    xb[(size_t)(r0 + r) * 256 + c] = f2bf(v);
                    if (n == 0 && wc == 0 && cl == 0) {
                        float d = v - 1.0f;
                        float sp = fmaxf(d, 0.0f) + log1pf(expf(-fabsf(d)));
                        out[(size_t)(r0 + r) * 4] = sp;
                    }
                }
            }
        }
    }
}

// ---------------- fused G3+G4 (round-9 proven, FROZEN):
// phase1: h0 = relu(x@W0 + deW0) -> sH0 ; acc2 = x@W1[256:512]  (af reused, two B passes)
// phase2: acc2 += h0@W1[0:256] ; h1 = relu(acc2 + deW1) -> LDS ; rgb = sigmoid(h1@Wr+br)
__global__ __launch_bounds__(512, 2) void k_g34(const unsigned short* __restrict__ xb,
                                                const unsigned short* __restrict__ W0t,  // [256][256]
                                                const unsigned short* __restrict__ W1t,  // [256][512]
                                                const float* __restrict__ deW0,
                                                const float* __restrict__ deW1,
                                                const float* __restrict__ Wr,
                                                const float* __restrict__ br,
                                                float* __restrict__ out) {
    __shared__ __align__(16) unsigned short sH0[4][64 * 72];  // 36864 B (h1 [64][264] reuses this)
    __shared__ __align__(16) unsigned short sB[256 * 40];     // 20480 B, K=32 chunk
    __shared__ float sWr[768];                                // 3072 B
    int t = threadIdx.x;
    int lane = t & 63, wid = t >> 6;
    int wr = wid >> 2, wc = wid & 3;   // wave tile 32 x 64
    int cl = lane & 15, q = lane >> 4;
    int r0 = blockIdx.x * 64;
    for (int i = t; i < 768; i += 512) sWr[i] = Wr[i];

    int bc = t >> 1, bh = (t & 1) * 16;  // B stage: col, k-sub
    const unsigned short* W0p = W0t + (size_t)bc * 256 + bh;
    const unsigned short* W1p = W1t + (size_t)bc * 512 + bh;
    const unsigned short* Arow0 = xb + (size_t)(r0 + wr * 32 + cl) * 256 + q * 8;
    const unsigned short* Arow1 = Arow0 + 16 * 256;

    f32x4 acc1[2][4] = {};
    f32x4 acc2[2][4] = {};

    // ---- phase 1: K=256 in 8 chunks of 32
    for (int c8 = 0; c8 < 8; ++c8) {
        int k0 = c8 * 32;
        bf16x8 af[2];
        af[0] = *(const bf16x8*)(Arow0 + k0);
        af[1] = *(const bf16x8*)(Arow1 + k0);
        int4 b0 = *(const int4*)(W0p + k0);
        int4 b1 = *(const int4*)(W0p + k0 + 8);
        __syncthreads();
        *(int4*)(sB + bc * 40 + bh)     = b0;
        *(int4*)(sB + bc * 40 + bh + 8) = b1;
        __syncthreads();
        {
            bf16x8 bf[4];
#pragma unroll
            for (int n = 0; n < 4; ++n)
                bf[n] = *(const bf16x8*)(sB + (wc * 64 + n * 16 + cl) * 40 + q * 8);
#pragma unroll
            for (int m = 0; m < 2; ++m)
#pragma unroll
                for (int n = 0; n < 4; ++n)
                    acc1[m][n] = __builtin_amdgcn_mfma_f32_16x16x32_bf16(af[m], bf[n], acc1[m][n], 0, 0, 0);
        }
        int4 c0 = *(const int4*)(W1p + 256 + k0);
        int4 c1 = *(const int4*)(W1p + 256 + k0 + 8);
        __syncthreads();
        *(int4*)(sB + bc * 40 + bh)     = c0;
        *(int4*)(sB + bc * 40 + bh + 8) = c1;
        __syncthreads();
        {
            bf16x8 bf[4];
#pragma unroll
            for (int n = 0; n < 4; ++n)
                bf[n] = *(const bf16x8*)(sB + (wc * 64 + n * 16 + cl) * 40 + q * 8);
#pragma unroll
            for (int m = 0; m < 2; ++m)
#pragma unroll
                for (int n = 0; n < 4; ++n)
                    acc2[m][n] = __builtin_amdgcn_mfma_f32_16x16x32_bf16(af[m], bf[n], acc2[m][n], 0, 0, 0);
        }
    }
    // ---- h0 epilogue -> sH0 K-tiles (each wave writes tile wc only)
#pragma unroll
    for (int m = 0; m < 2; ++m) {
        int rb = wr * 32 + m * 16;
        const float* dwp = deW0 + (size_t)((r0 + rb) >> 5) * 256;
#pragma unroll
        for (int n = 0; n < 4; ++n) {
            int c = wc * 64 + n * 16 + cl;
            float dv = dwp[c];
#pragma unroll
            for (int i = 0; i < 4; ++i) {
                int r = rb + q * 4 + i;
                sH0[wc][r * 72 + (c & 63)] = f2bf(fmaxf(acc1[m][n][i] + dv, 0.f));
            }
        }
    }
    __syncthreads();
    // ---- phase 2: acc2 += h0 @ W1lo, 8 chunks of 32
    for (int c8 = 0; c8 < 8; ++c8) {
        int k0 = c8 * 32;
        bf16x8 af[2];
#pragma unroll
        for (int m = 0; m < 2; ++m)
            af[m] = *(const bf16x8*)(&sH0[k0 >> 6][(wr * 32 + m * 16 + cl) * 72 + (k0 & 63) + q * 8]);
        int4 b0 = *(const int4*)(W1p + k0);
        int4 b1 = *(const int4*)(W1p + k0 + 8);
        __syncthreads();
        *(int4*)(sB + bc * 40 + bh)     = b0;
        *(int4*)(sB + bc * 40 + bh + 8) = b1;
        __syncthreads();
        bf16x8 bf[4];
#pragma unroll
        for (int n = 0; n < 4; ++n)
            bf[n] = *(const bf16x8*)(sB + (wc * 64 + n * 16 + cl) * 40 + q * 8);
#pragma unroll
        for (int m = 0; m < 2; ++m)
#pragma unroll
            for (int n = 0; n < 4; ++n)
                acc2[m][n] = __builtin_amdgcn_mfma_f32_16x16x32_bf16(af[m], bf[n], acc2[m][n], 0, 0, 0);
    }
    __syncthreads();  // all sH0 reads done before reuse as h1
    // ---- h1 epilogue -> [64][264] over sH0, then fused Wr reduce
    unsigned short* sH1 = &sH0[0][0];
#pragma unroll
    for (int m = 0; m < 2; ++m) {
        int rb = wr * 32 + m * 16;
        const float* dwp = deW1 + (size_t)((r0 + rb) >> 5) * 256;
#pragma unroll
        for (int n = 0; n < 4; ++n) {
            int c = wc * 64 + n * 16 + cl;
            float dv = dwp[c];
#pragma unroll
            for (int i = 0; i < 4; ++i) {
                int r = rb + q * 4 + i;
                sH1[r * 264 + c] = f2bf(fmaxf(acc2[m][n][i] + dv, 0.f));
            }
        }
    }
    __syncthreads();
    if (t < 384) {  // 64 rows x 3 ch x 2 halves
        int r = t / 6, rem = t % 6, j = rem >> 1, half = rem & 1;
        float a = 0.f;
        const unsigned short* hp = sH1 + r * 264 + half * 128;
        const float* wp = sWr + (half * 128) * 3 + j;
        for (int c = 0; c < 128; ++c) a += bf2f(hp[c]) * wp[c * 3];
        a += __shfl_xor(a, 1);
        if (!half) {
            a += br[j];
            float s = 1.0f / (1.0f + expf(-a));
            out[(size_t)(r0 + r) * 4 + 1 + j] = s * 1.002f - 0.001f;
        }
    }
}

extern "C" void kernel_launch(void* const* d_in, const int* in_sizes, int n_in,
                              void* d_out, int out_size, void* d_ws, size_t ws_size,
                              hipStream_t stream) {
    const float* coords   = (const float*)d_in[0];
    const float* viewdirs = (const float*)d_in[1];
    const float* table    = (const float*)d_in[2];
    const float* Wd0      = (const float*)d_in[3];
    const float* bd0      = (const float*)d_in[4];
    const float* Wd1      = (const float*)d_in[5];
    const float* bd1      = (const float*)d_in[6];
    const float* W0       = (const float*)d_in[7];
    const float* b0       = (const float*)d_in[8];
    const float* W1       = (const float*)d_in[9];
    const float* b1       = (const float*)d_in[10];
    const float* Wr       = (const float*)d_in[11];
    const float* br       = (const float*)d_in[12];
    float* out = (float*)d_out;

    const size_t N = NPTS;
    unsigned short* ws = (unsigned short*)d_ws;
    unsigned short* featsb = ws;                       // N*64 bf16 (padded K)
    unsigned short* xb     = featsb + N * 64;          // N*256 bf16
    float* deW0 = (float*)(xb + N * 256);              // 4096*256 f32
    float* deW1 = deW0 + 4096 * 256;                   // 4096*256 f32
    unsigned short* W0t  = (unsigned short*)(deW1 + 4096 * 256); // 256*256
    unsigned short* W1t  = W0t + 65536;                // 256*512
    unsigned short* Wd0t = W1t + 131072;               // 64*72
    unsigned short* Wd1t = Wd0t + 4608;                // 256*72

    k_front<<<1280, 256, 0, stream>>>(coords, table, featsb,
                                      W0, W1, Wd0, Wd1, W0t, W1t, Wd0t, Wd1t,
                                      viewdirs, b0, b1, deW0, deW1);
    k_mlp0<<<NPTS / 64, 512, 0, stream>>>(featsb, Wd0t, Wd1t, bd0, bd1, xb, out);
    k_g34<<<NPTS / 64, 512, 0, stream>>>(xb, W0t, W1t, deW0, deW1, Wr, br, out);
}